// Round 10
// baseline (461.284 us; speedup 1.0000x reference)
//
#include <hip/hip_runtime.h>

typedef unsigned short u16;
typedef unsigned int u32;
typedef short short8v __attribute__((ext_vector_type(8)));
typedef float float4v __attribute__((ext_vector_type(4)));

#define N_NODES 50000
#define E_EDGES 400000
#define R_REL   500
#define NKEYS   100000          // cntI[50000] | cntO[50000]
#define SCAN_B  98              // 98*1024 = 100352 >= NKEYS
#define SEG     ((size_t)N_NODES * 128)

__device__ __forceinline__ float bl(u32 u){ return __uint_as_float(u << 16); }
__device__ __forceinline__ float bh(u32 u){ return __uint_as_float(u & 0xffff0000u); }
__device__ __forceinline__ u16 f2b(float f){
    u32 u = __float_as_uint(f);
    return (u16)((u + 0x7fffu + ((u >> 16) & 1u)) >> 16);
}
__device__ __forceinline__ u32 pk2(float a, float b){ return (u32)f2b(a) | ((u32)f2b(b) << 16); }
__device__ __forceinline__ float lrelu(float x){ return x > 0.f ? x : 0.01f * x; }

// ---------------- normalize x -> bf16 padded [N,128] ----------------
__global__ void k_norm_x(const float* __restrict__ x, u16* __restrict__ xnb){
    int wid = threadIdx.x >> 6, l = threadIdx.x & 63;
    int n = blockIdx.x * 4 + wid;
    if (n >= N_NODES) return;
    float v0 = x[(size_t)n * 100 + l];
    float v1 = (l + 64 < 100) ? x[(size_t)n * 100 + 64 + l] : 0.f;
    float ss = v0 * v0 + v1 * v1;
    #pragma unroll
    for (int m = 32; m; m >>= 1) ss += __shfl_xor(ss, m);
    float s = 1.f / fmaxf(sqrtf(ss), 1e-12f);
    xnb[(size_t)n * 128 + l] = f2b(v0 * s);
    xnb[(size_t)n * 128 + 64 + l] = (l + 64 < 100) ? f2b(v1 * s) : (u16)0;
}

// ---------------- build concatenated weights (bf16) + attcat tables ----------------
__global__ void k_build_wcat(const float* __restrict__ W1i, const float* __restrict__ W1o,
                             const float* __restrict__ W2i, const float* __restrict__ W2o,
                             const float* __restrict__ We,
                             const float* __restrict__ a1i, const float* __restrict__ a1o,
                             const float* __restrict__ a2i, const float* __restrict__ a2o,
                             u16* __restrict__ wc1, u16* __restrict__ wc2,
                             float* __restrict__ attcat){
    int idx = blockIdx.x * blockDim.x + threadIdx.x;
    if (idx < 576 * 128){
        int r = idx >> 7, k = idx & 127;
        float v = 0.f;
        if (r < 512){
            int seg = r >> 7, rr = r & 127;
            const float* W = (seg < 2) ? W1i : W1o;
            int off = (seg & 1) ? 100 : 0;
            if (k < 100) v = W[(size_t)rr * 300 + off + k];
        } else {
            int rr = r - 512;
            if (k < 100) v = We[(size_t)rr * 100 + k];
        }
        wc1[idx] = f2b(v);
    } else if (idx < 576 * 128 + 512 * 128){
        int j = idx - 576 * 128;
        int r = j >> 7, k = j & 127;
        int seg = r >> 7, rr = r & 127;
        const float* W = (seg < 2) ? W2i : W2o;
        int off = (seg & 1) ? 128 : 0;
        wc2[j] = f2b(W[(size_t)rr * 356 + off + k]);
    } else if (idx < 576 * 128 + 512 * 128 + 1024){
        int j = idx - (576 * 128 + 512 * 128);
        int s = j >> 9, cc = j & 511;
        const float* a = s ? ((cc < 256) ? a2i : a2o) : ((cc < 256) ? a1i : a1o);
        attcat[j] = a[cc & 127];
    }
}

// ---------------- relation tables ----------------
__global__ void k_pg(const float* __restrict__ g,
                     const float* __restrict__ W1i, const float* __restrict__ W1o,
                     const float* __restrict__ W2i, const float* __restrict__ W2o,
                     const float* __restrict__ b1i, const float* __restrict__ b1o,
                     const float* __restrict__ b2i, const float* __restrict__ b2o,
                     const float* __restrict__ a1i, const float* __restrict__ a1o,
                     const float* __restrict__ a2i, const float* __restrict__ a2o,
                     float* __restrict__ Pg, float* __restrict__ qg){
    int bid = blockIdx.x;
    int r = bid >> 2, t = bid & 3;
    const float *W, *b, *att; int ld, off;
    if (t == 0){ W = W1i; ld = 300; off = 200; b = b1i; att = a1i; }
    else if (t == 1){ W = W1o; ld = 300; off = 200; b = b1o; att = a1o; }
    else if (t == 2){ W = W2i; ld = 356; off = 256; b = b2i; att = a2i; }
    else { W = W2o; ld = 356; off = 256; b = b2o; att = a2o; }
    __shared__ float gs[100];
    __shared__ float red[128];
    int j = threadIdx.x; // 128 threads
    if (j < 100) gs[j] = g[(size_t)r * 100 + j];
    __syncthreads();
    float acc = b[j];
    #pragma unroll 4
    for (int k = 0; k < 100; ++k) acc += gs[k] * W[(size_t)j * ld + off + k];
    Pg[((size_t)t * R_REL + r) * 128 + j] = acc;
    red[j] = att[j] * acc;
    __syncthreads();
    if (j < 2){
        float s = 0.f;
        for (int k = 0; k < 64; ++k) s += red[j * 64 + k];
        qg[((size_t)t * R_REL + r) * 2 + j] = s;
    }
}

// ---------------- g_prime = g @ Wr^T + br -> out (f32) ----------------
__global__ void k_gprime(const float* __restrict__ g, const float* __restrict__ Wr,
                         const float* __restrict__ br, float* __restrict__ out){
    int r = blockIdx.x, j = threadIdx.x; // 128 threads
    __shared__ float gs[100];
    if (j < 100) gs[j] = g[(size_t)r * 100 + j];
    __syncthreads();
    float acc = br[j];
    #pragma unroll 4
    for (int k = 0; k < 100; ++k) acc += gs[k] * Wr[(size_t)j * 100 + k];
    out[(size_t)N_NODES * 128 + (size_t)r * 128 + j] = acc;
}

// ---------------- node GEMM: packed segment-major output + fused q scalars ----------------
// q[n][g] (g = cc>>6 = t*2+h) accumulated from attcat[cc]*C[n][cc] for cc < 512.
__launch_bounds__(256)
__global__ void k_gemm(const u16* __restrict__ A, const u16* __restrict__ W,
                       const float* __restrict__ attcat,
                       u16* __restrict__ NPt, float* __restrict__ q, int M, int NN){
    int l = threadIdx.x & 63, w = threadIdx.x >> 6;
    int rb = blockIdx.x * 64 + w * 16;
    int ar = rb + (l & 15); if (ar >= M) ar = M - 1;
    const u16* Ap = A + (size_t)ar * 128 + (l >> 4) * 8;
    short8v a0 = *(const short8v*)(Ap);
    short8v a1 = *(const short8v*)(Ap + 32);
    short8v a2 = *(const short8v*)(Ap + 64);
    short8v a3 = *(const short8v*)(Ap + 96);
    float qa[4] = {0.f, 0.f, 0.f, 0.f};
    int ntc = NN >> 4;
    for (int nt = 0; nt < ntc; ++nt){
        const u16* Wp = W + (size_t)(nt * 16 + (l & 15)) * 128 + (l >> 4) * 8;
        short8v b0 = *(const short8v*)(Wp);
        short8v b1 = *(const short8v*)(Wp + 32);
        short8v b2 = *(const short8v*)(Wp + 64);
        short8v b3 = *(const short8v*)(Wp + 96);
        float4v acc = {0.f, 0.f, 0.f, 0.f};
        acc = __builtin_amdgcn_mfma_f32_16x16x32_bf16(a0, b0, acc, 0, 0, 0);
        acc = __builtin_amdgcn_mfma_f32_16x16x32_bf16(a1, b1, acc, 0, 0, 0);
        acc = __builtin_amdgcn_mfma_f32_16x16x32_bf16(a2, b2, acc, 0, 0, 0);
        acc = __builtin_amdgcn_mfma_f32_16x16x32_bf16(a3, b3, acc, 0, 0, 0);
        int cc = nt * 16 + (l & 15);
        int seg = cc >> 7;
        int rr0 = rb + (l >> 4) * 4;
        #pragma unroll
        for (int r = 0; r < 4; ++r){
            int rr = rr0 + r;
            if (rr < M){
                if (seg < 4) NPt[(size_t)seg * SEG + (size_t)rr * 128 + (cc & 127)] = f2b(acc[r]);
                else         NPt[4 * SEG + (size_t)rr * 64 + (cc & 63)] = f2b(acc[r]);
            }
        }
        int g = nt >> 2;
        if (g < 8){
            float av = attcat[cc];
            #pragma unroll
            for (int r = 0; r < 4; ++r) qa[r] += av * acc[r];
            if ((nt & 3) == 3){
                #pragma unroll
                for (int r = 0; r < 4; ++r){
                    float s = qa[r];
                    s += __shfl_xor(s, 1); s += __shfl_xor(s, 2);
                    s += __shfl_xor(s, 4); s += __shfl_xor(s, 8);
                    if ((l & 15) == 0){
                        int rr = rr0 + r;
                        if (rr < M) q[(size_t)rr * 8 + g] = s;
                    }
                    qa[r] = 0.f;
                }
            }
        }
    }
}

// ---------------- CSR build: histogram / scan / static position records ----------------
__global__ void k_hist(const int* __restrict__ ei, u32* __restrict__ cnt){
    int e = blockIdx.x * blockDim.x + threadIdx.x;
    if (e >= E_EDGES) return;
    atomicAdd(&cnt[ei[E_EDGES + e]], 1u);          // in-aggregation key: col
    atomicAdd(&cnt[N_NODES + ei[e]], 1u);          // out-aggregation key: row
}

__launch_bounds__(1024)
__global__ void k_scan1(const u32* __restrict__ cnt, u32* __restrict__ off, u32* __restrict__ bsum){
    __shared__ u32 sh[1024];
    int t = threadIdx.x, b = blockIdx.x, idx = b * 1024 + t;
    u32 v = cnt[idx];
    sh[t] = v; __syncthreads();
    #pragma unroll
    for (int d = 1; d < 1024; d <<= 1){
        u32 add = (t >= d) ? sh[t - d] : 0;
        __syncthreads();
        sh[t] += add;
        __syncthreads();
    }
    off[idx] = sh[t] - v;                          // exclusive within block
    if (t == 1023) bsum[b] = sh[1023];
}

__global__ void k_scan2(u32* __restrict__ bsum){
    if (threadIdx.x == 0){
        u32 run = 0;
        for (int i = 0; i < SCAN_B; ++i){ u32 t = bsum[i]; bsum[i] = run; run += t; }
    }
}

__launch_bounds__(1024)
__global__ void k_scan3(u32* __restrict__ off, const u32* __restrict__ bsum){
    int idx = blockIdx.x * 1024 + threadIdx.x;
    off[idx] += bsum[blockIdx.x];
}

// static sorted-position records (once): Pso[p] = other | et<<20
__global__ void k_pos(const int* __restrict__ ei, const int* __restrict__ ety,
                      u32* __restrict__ cur, u32* __restrict__ Pso){
    int e = blockIdx.x * blockDim.x + threadIdx.x;
    if (e >= E_EDGES) return;
    u32 row = (u32)ei[e], col = (u32)ei[E_EDGES + e];
    u32 etb = (u32)ety[e] << 20;
    u32 pI = atomicAdd(&cur[col], 1u);             // in-list keyed by col
    Pso[pI] = row | etb;
    u32 pO = atomicAdd(&cur[N_NODES + row], 1u);   // out-list keyed by row
    Pso[pO] = col | etb;
}

// ---------------- denominators by CSR duality: compute exps in place ----------------
// dI[n] = sum over n's OUT-list (edges row=n, oth=col): exp(lrelu(q[n][h]+q[oth][2+h]+qgI))
// dO[n] = sum over n's IN-list  (edges col=n, oth=row): exp(lrelu(q[n][4+h]+q[oth][6+h]+qgO))
__global__ void k_denom(const u32* __restrict__ off, const u32* __restrict__ Pso,
                        const float* __restrict__ q,
                        const float* __restrict__ qgI, const float* __restrict__ qgO,
                        float* __restrict__ rdI, float* __restrict__ rdO){
    int n = blockIdx.x * blockDim.x + threadIdx.x;
    if (n >= N_NODES) return;
    const float* qn = q + (size_t)n * 8;
    float qn0 = qn[0], qn1 = qn[1], qn4 = qn[4], qn5 = qn[5];
    float s0 = 0.f, s1 = 0.f;
    for (u32 p = off[N_NODES + n]; p < off[N_NODES + n + 1]; ++p){
        u32 so = Pso[p]; u32 oth = so & 0xFFFFFu, et = so >> 20;
        float2 qo = *(const float2*)(q + (size_t)oth * 8 + 2);
        float2 gq = *(const float2*)(qgI + (size_t)et * 2);
        s0 += expf(lrelu(qn0 + qo.x + gq.x));
        s1 += expf(lrelu(qn1 + qo.y + gq.y));
    }
    rdI[(size_t)n * 2 + 0] = (s0 > 0.f) ? 1.f / s0 : 0.f;
    rdI[(size_t)n * 2 + 1] = (s1 > 0.f) ? 1.f / s1 : 0.f;
    float t0 = 0.f, t1 = 0.f;
    for (u32 p = off[n]; p < off[n + 1]; ++p){
        u32 so = Pso[p]; u32 oth = so & 0xFFFFFu, et = so >> 20;
        float2 qo = *(const float2*)(q + (size_t)oth * 8 + 6);
        float2 gq = *(const float2*)(qgO + (size_t)et * 2);
        t0 += expf(lrelu(qn4 + qo.x + gq.x));
        t1 += expf(lrelu(qn5 + qo.y + gq.y));
    }
    rdO[(size_t)n * 2 + 0] = (t0 > 0.f) ? 1.f / t0 : 0.f;
    rdO[(size_t)n * 2 + 1] = (t1 > 0.f) ? 1.f / t1 : 0.f;
}

// ---------------- fused gather-aggregate + node epilogue ----------------
// preload lane computes the edge's softmax weights w0,w1 = exp(lrelu(...))*rd and
// packs them bf16 into one u32; consume: 2 shfl + Pa gather + Pg read.
__launch_bounds__(256)
__global__ void k_agg(const u32* __restrict__ off, const u32* __restrict__ Pso,
                      const float* __restrict__ q,
                      const float* __restrict__ qgI, const float* __restrict__ qgO,
                      const u16* __restrict__ NPt,
                      const float* __restrict__ PgI, const float* __restrict__ PgO,
                      const float* __restrict__ rdI, const float* __restrict__ rdO,
                      int final_stage,
                      const u16* __restrict__ NPt1, const float* __restrict__ be,
                      u16* __restrict__ h1b, float* __restrict__ out){
    int wid = threadIdx.x >> 6, l = threadIdx.x & 63;
    int n = blockIdx.x * 4 + wid;
    if (n >= N_NODES) return;
    int h = l >> 5, d0 = l * 2;
    const u16* PaI = NPt;
    const u16* PbI = NPt + SEG;
    const u16* PaO = NPt + 2 * SEG;
    const u16* PbO = NPt + 3 * SEG;
    u32 pbi = *(const u32*)(PbI + (size_t)n * 128 + d0);
    u32 pbo = *(const u32*)(PbO + (size_t)n * 128 + d0);
    float2 qn2 = *(const float2*)(q + (size_t)n * 8 + 2);   // q[n][2..3]
    float2 qn6 = *(const float2*)(q + (size_t)n * 8 + 6);   // q[n][6..7]

    float a0 = 0.f, a1 = 0.f, sai = 0.f;
    {
        u32 s0 = off[n], deg = off[n + 1] - s0;
        for (u32 base = 0; base < deg; base += 64){
            u32 k = base + (u32)l;
            u32 so = 0u, wp = 0u;
            if (k < deg){
                u32 idx = s0 + k;
                so = __builtin_nontemporal_load(Pso + idx);
                u32 oth = so & 0xFFFFFu, et = so >> 20;
                float2 qo = *(const float2*)(q + (size_t)oth * 8);       // q[oth][0..1]
                float2 gq = *(const float2*)(qgI + (size_t)et * 2);
                float2 rd2 = *(const float2*)(rdI + (size_t)oth * 2);
                float w0 = expf(lrelu(qo.x + qn2.x + gq.x)) * rd2.x;
                float w1 = expf(lrelu(qo.y + qn2.y + gq.y)) * rd2.y;
                wp = pk2(w0, w1);
            }
            int cnt = (int)((deg - base < 64u) ? (deg - base) : 64u);
            for (int c = 0; c < cnt; c += 8){
                float wj[8]; u32 pa[8]; float2 gv[8];
                #pragma unroll
                for (int j = 0; j < 8; ++j){
                    u32 s = __shfl(so, c + j);
                    u32 wv = __shfl(wp, c + j);
                    u32 oth = s & 0xFFFFFu, et = s >> 20;
                    pa[j] = *(const u32*)(PaI + (size_t)oth * 128 + d0);
                    gv[j] = *(const float2*)(PgI + (size_t)et * 128 + d0);
                    wj[j] = h ? bh(wv) : bl(wv);
                }
                #pragma unroll
                for (int j = 0; j < 8; ++j){
                    a0 += wj[j] * (bl(pa[j]) + gv[j].x);
                    a1 += wj[j] * (bh(pa[j]) + gv[j].y);
                    sai += wj[j];
                }
            }
        }
    }
    a0 += sai * bl(pbi);
    a1 += sai * bh(pbi);

    float b0 = 0.f, b1 = 0.f, sao = 0.f;
    {
        u32 s0 = off[N_NODES + n], deg = off[N_NODES + n + 1] - s0;
        for (u32 base = 0; base < deg; base += 64){
            u32 k = base + (u32)l;
            u32 so = 0u, wp = 0u;
            if (k < deg){
                u32 idx = s0 + k;
                so = __builtin_nontemporal_load(Pso + idx);
                u32 oth = so & 0xFFFFFu, et = so >> 20;
                float2 qo = *(const float2*)(q + (size_t)oth * 8 + 4);   // q[oth][4..5]
                float2 gq = *(const float2*)(qgO + (size_t)et * 2);
                float2 rd2 = *(const float2*)(rdO + (size_t)oth * 2);
                float w0 = expf(lrelu(qo.x + qn6.x + gq.x)) * rd2.x;
                float w1 = expf(lrelu(qo.y + qn6.y + gq.y)) * rd2.y;
                wp = pk2(w0, w1);
            }
            int cnt = (int)((deg - base < 64u) ? (deg - base) : 64u);
            for (int c = 0; c < cnt; c += 8){
                float wj[8]; u32 pa[8]; float2 gv[8];
                #pragma unroll
                for (int j = 0; j < 8; ++j){
                    u32 s = __shfl(so, c + j);
                    u32 wv = __shfl(wp, c + j);
                    u32 oth = s & 0xFFFFFu, et = s >> 20;
                    pa[j] = *(const u32*)(PaO + (size_t)oth * 128 + d0);
                    gv[j] = *(const float2*)(PgO + (size_t)et * 128 + d0);
                    wj[j] = h ? bh(wv) : bl(wv);
                }
                #pragma unroll
                for (int j = 0; j < 8; ++j){
                    b0 += wj[j] * (bl(pa[j]) + gv[j].x);
                    b1 += wj[j] * (bh(pa[j]) + gv[j].y);
                    sao += wj[j];
                }
            }
        }
    }
    b0 += sao * bl(pbo);
    b1 += sao * bh(pbo);

    float vx = lrelu(0.5f * (a0 + b0));
    float vy = lrelu(0.5f * (a1 + b1));
    float ss = vx * vx + vy * vy;
    #pragma unroll
    for (int m = 16; m; m >>= 1) ss += __shfl_xor(ss, m);    // per-head (32-lane) reduce
    float s2 = 1.f / fmaxf(sqrtf(ss), 1e-12f);
    if (!final_stage){
        *(u32*)(h1b + (size_t)n * 128 + d0) = pk2(vx * s2, vy * s2);
    } else {
        float h20 = vx * s2, h21 = vy * s2;
        int o0 = d0 & 63;
        u32 ue = *(const u32*)(NPt1 + 4 * SEG + (size_t)n * 64 + o0);
        float hp0 = bl(ue) + be[o0] + h20;
        float hp1 = bh(ue) + be[o0 + 1] + h21;
        float st = hp0 * hp0 + hp1 * hp1;
        #pragma unroll
        for (int m = 32; m; m >>= 1) st += __shfl_xor(st, m); // full 128-dim norm
        float s = 1.f / fmaxf(sqrtf(st), 1e-12f);
        float2 o; o.x = hp0 * s; o.y = hp1 * s;
        *(float2*)(out + (size_t)n * 128 + d0) = o;
    }
}

extern "C" void kernel_launch(void* const* d_in, const int* in_sizes, int n_in,
                              void* d_out, int out_size, void* d_ws, size_t ws_size,
                              hipStream_t stream){
    const float* x   = (const float*)d_in[0];
    const float* g   = (const float*)d_in[1];
    const int*   ei  = (const int*)d_in[2];
    const int*   ety = (const int*)d_in[3];
    const float* W1i = (const float*)d_in[4];
    const float* b1i = (const float*)d_in[5];
    const float* a1i = (const float*)d_in[6];
    const float* W1o = (const float*)d_in[7];
    const float* b1o = (const float*)d_in[8];
    const float* a1o = (const float*)d_in[9];
    const float* W2i = (const float*)d_in[10];
    const float* b2i = (const float*)d_in[11];
    const float* a2i = (const float*)d_in[12];
    const float* W2o = (const float*)d_in[13];
    const float* b2o = (const float*)d_in[14];
    const float* a2o = (const float*)d_in[15];
    const float* We  = (const float*)d_in[16];
    const float* be  = (const float*)d_in[17];
    const float* Wr  = (const float*)d_in[18];
    const float* br  = (const float*)d_in[19];
    float* out = (float*)d_out;

    char* ws = (char*)d_ws;
    size_t off_b = 0;
    auto carve = [&](size_t bytes) -> char* {
        char* p = ws + off_b;
        off_b += (bytes + 255) & ~(size_t)255;
        return p;
    };
    u16*    xnb   = (u16*)carve((size_t)N_NODES * 128 * 2);
    u16*    wc1   = (u16*)carve((size_t)576 * 128 * 2);
    u16*    wc2   = (u16*)carve((size_t)512 * 128 * 2);
    float*  attct = (float*)carve((size_t)1024 * 4);
    u16*    NPt1  = (u16*)carve((SEG * 4 + (size_t)N_NODES * 64) * 2);  // 4 segs + entity
    u16*    NPt2  = (u16*)carve(SEG * 4 * 2);
    u16*    h1b   = (u16*)carve((size_t)N_NODES * 128 * 2);
    float*  q     = (float*)carve((size_t)N_NODES * 8 * 4);
    float*  Pg    = (float*)carve((size_t)4 * R_REL * 128 * 4);
    float*  qg    = (float*)carve((size_t)4 * R_REL * 2 * 4);
    u32*    cnt   = (u32*)carve((size_t)SCAN_B * 1024 * 4);    // zeroed, padded
    u32*    offA  = (u32*)carve((size_t)SCAN_B * 1024 * 4);    // exclusive scan
    u32*    cur   = (u32*)carve((size_t)NKEYS * 4);            // position cursors
    u32*    bsum  = (u32*)carve((size_t)SCAN_B * 4);
    u32*    Pso   = (u32*)carve((size_t)2 * E_EDGES * 4);      // other|et<<20 (static)
    float*  rdI   = (float*)carve((size_t)N_NODES * 2 * 4);    // reciprocal denoms
    float*  rdO   = (float*)carve((size_t)N_NODES * 2 * 4);

    // ---------------- stage 0: prep (CSR positions + tables + GEMM input) ----------------
    hipMemsetAsync(cnt, 0, (size_t)SCAN_B * 1024 * 4, stream);
    k_hist<<<1563, 256, 0, stream>>>(ei, cnt);
    k_scan1<<<SCAN_B, 1024, 0, stream>>>(cnt, offA, bsum);
    k_scan2<<<1, 64, 0, stream>>>(bsum);
    k_scan3<<<SCAN_B, 1024, 0, stream>>>(offA, bsum);
    hipMemcpyAsync(cur, offA, (size_t)NKEYS * 4, hipMemcpyDeviceToDevice, stream);
    k_pos<<<1563, 256, 0, stream>>>(ei, ety, cur, Pso);

    k_norm_x<<<12500, 256, 0, stream>>>(x, xnb);
    k_build_wcat<<<548, 256, 0, stream>>>(W1i, W1o, W2i, W2o, We,
                                          a1i, a1o, a2i, a2o, wc1, wc2, attct);
    k_pg<<<2000, 128, 0, stream>>>(g, W1i, W1o, W2i, W2o, b1i, b1o, b2i, b2o,
                                   a1i, a1o, a2i, a2o, Pg, qg);
    k_gprime<<<500, 128, 0, stream>>>(g, Wr, br, out);

    // ---------------- stage 1 ----------------
    k_gemm<<<782, 256, 0, stream>>>(xnb, wc1, attct, NPt1, q, N_NODES, 576);
    k_denom<<<196, 256, 0, stream>>>(offA, Pso, q, qg, qg + R_REL * 2, rdI, rdO);
    k_agg<<<12500, 256, 0, stream>>>(offA, Pso, q, qg, qg + R_REL * 2,
                                     NPt1, Pg, Pg + R_REL * 128,
                                     rdI, rdO, 0, NPt1, be, h1b, out);

    // ---------------- stage 2 ----------------
    k_gemm<<<782, 256, 0, stream>>>(h1b, wc2, attct + 512, NPt2, q, N_NODES, 512);
    k_denom<<<196, 256, 0, stream>>>(offA, Pso, q, qg + 2 * R_REL * 2, qg + 3 * R_REL * 2,
                                     rdI, rdO);
    k_agg<<<12500, 256, 0, stream>>>(offA, Pso, q, qg + 2 * R_REL * 2, qg + 3 * R_REL * 2,
                                     NPt2, Pg + 2 * R_REL * 128, Pg + 3 * R_REL * 128,
                                     rdI, rdO, 1, NPt1, be, h1b, out);
}

// Round 11
// 437.368 us; speedup vs baseline: 1.0547x; 1.0547x over previous
//
#include <hip/hip_runtime.h>

typedef unsigned short u16;
typedef unsigned int u32;
typedef short short8v __attribute__((ext_vector_type(8)));
typedef float float4v __attribute__((ext_vector_type(4)));

#define N_NODES 50000
#define E_EDGES 400000
#define R_REL   500
#define NKEYS   100000          // cntI[50000] | cntO[50000]
#define SCAN_B  98              // 98*1024 = 100352 >= NKEYS
#define SEG     ((size_t)N_NODES * 128)

__device__ __forceinline__ float bl(u32 u){ return __uint_as_float(u << 16); }
__device__ __forceinline__ float bh(u32 u){ return __uint_as_float(u & 0xffff0000u); }
__device__ __forceinline__ u16 f2b(float f){
    u32 u = __float_as_uint(f);
    return (u16)((u + 0x7fffu + ((u >> 16) & 1u)) >> 16);
}
__device__ __forceinline__ u32 pk2(float a, float b){ return (u32)f2b(a) | ((u32)f2b(b) << 16); }
__device__ __forceinline__ float lrelu(float x){ return x > 0.f ? x : 0.01f * x; }

// ---------------- normalize x -> bf16 padded [N,128] ----------------
__global__ void k_norm_x(const float* __restrict__ x, u16* __restrict__ xnb){
    int wid = threadIdx.x >> 6, l = threadIdx.x & 63;
    int n = blockIdx.x * 4 + wid;
    if (n >= N_NODES) return;
    float v0 = x[(size_t)n * 100 + l];
    float v1 = (l + 64 < 100) ? x[(size_t)n * 100 + 64 + l] : 0.f;
    float ss = v0 * v0 + v1 * v1;
    #pragma unroll
    for (int m = 32; m; m >>= 1) ss += __shfl_xor(ss, m);
    float s = 1.f / fmaxf(sqrtf(ss), 1e-12f);
    xnb[(size_t)n * 128 + l] = f2b(v0 * s);
    xnb[(size_t)n * 128 + 64 + l] = (l + 64 < 100) ? f2b(v1 * s) : (u16)0;
}

// ---------------- build concatenated weights (bf16) + attcat tables ----------------
__global__ void k_build_wcat(const float* __restrict__ W1i, const float* __restrict__ W1o,
                             const float* __restrict__ W2i, const float* __restrict__ W2o,
                             const float* __restrict__ We,
                             const float* __restrict__ a1i, const float* __restrict__ a1o,
                             const float* __restrict__ a2i, const float* __restrict__ a2o,
                             u16* __restrict__ wc1, u16* __restrict__ wc2,
                             float* __restrict__ attcat){
    int idx = blockIdx.x * blockDim.x + threadIdx.x;
    if (idx < 576 * 128){
        int r = idx >> 7, k = idx & 127;
        float v = 0.f;
        if (r < 512){
            int seg = r >> 7, rr = r & 127;
            const float* W = (seg < 2) ? W1i : W1o;
            int off = (seg & 1) ? 100 : 0;
            if (k < 100) v = W[(size_t)rr * 300 + off + k];
        } else {
            int rr = r - 512;
            if (k < 100) v = We[(size_t)rr * 100 + k];
        }
        wc1[idx] = f2b(v);
    } else if (idx < 576 * 128 + 512 * 128){
        int j = idx - 576 * 128;
        int r = j >> 7, k = j & 127;
        int seg = r >> 7, rr = r & 127;
        const float* W = (seg < 2) ? W2i : W2o;
        int off = (seg & 1) ? 128 : 0;
        wc2[j] = f2b(W[(size_t)rr * 356 + off + k]);
    } else if (idx < 576 * 128 + 512 * 128 + 1024){
        int j = idx - (576 * 128 + 512 * 128);
        int s = j >> 9, cc = j & 511;
        const float* a = s ? ((cc < 256) ? a2i : a2o) : ((cc < 256) ? a1i : a1o);
        attcat[j] = a[cc & 127];
    }
}

// ---------------- relation tables ----------------
__global__ void k_pg(const float* __restrict__ g,
                     const float* __restrict__ W1i, const float* __restrict__ W1o,
                     const float* __restrict__ W2i, const float* __restrict__ W2o,
                     const float* __restrict__ b1i, const float* __restrict__ b1o,
                     const float* __restrict__ b2i, const float* __restrict__ b2o,
                     const float* __restrict__ a1i, const float* __restrict__ a1o,
                     const float* __restrict__ a2i, const float* __restrict__ a2o,
                     float* __restrict__ Pg, float* __restrict__ qg){
    int bid = blockIdx.x;
    int r = bid >> 2, t = bid & 3;
    const float *W, *b, *att; int ld, off;
    if (t == 0){ W = W1i; ld = 300; off = 200; b = b1i; att = a1i; }
    else if (t == 1){ W = W1o; ld = 300; off = 200; b = b1o; att = a1o; }
    else if (t == 2){ W = W2i; ld = 356; off = 256; b = b2i; att = a2i; }
    else { W = W2o; ld = 356; off = 256; b = b2o; att = a2o; }
    __shared__ float gs[100];
    __shared__ float red[128];
    int j = threadIdx.x; // 128 threads
    if (j < 100) gs[j] = g[(size_t)r * 100 + j];
    __syncthreads();
    float acc = b[j];
    #pragma unroll 4
    for (int k = 0; k < 100; ++k) acc += gs[k] * W[(size_t)j * ld + off + k];
    Pg[((size_t)t * R_REL + r) * 128 + j] = acc;
    red[j] = att[j] * acc;
    __syncthreads();
    if (j < 2){
        float s = 0.f;
        for (int k = 0; k < 64; ++k) s += red[j * 64 + k];
        qg[((size_t)t * R_REL + r) * 2 + j] = s;
    }
}

// ---------------- g_prime = g @ Wr^T + br -> out (f32) ----------------
__global__ void k_gprime(const float* __restrict__ g, const float* __restrict__ Wr,
                         const float* __restrict__ br, float* __restrict__ out){
    int r = blockIdx.x, j = threadIdx.x; // 128 threads
    __shared__ float gs[100];
    if (j < 100) gs[j] = g[(size_t)r * 100 + j];
    __syncthreads();
    float acc = br[j];
    #pragma unroll 4
    for (int k = 0; k < 100; ++k) acc += gs[k] * Wr[(size_t)j * 100 + k];
    out[(size_t)N_NODES * 128 + (size_t)r * 128 + j] = acc;
}

// ---------------- node GEMM: packed segment-major output + fused q scalars ----------------
__launch_bounds__(256)
__global__ void k_gemm(const u16* __restrict__ A, const u16* __restrict__ W,
                       const float* __restrict__ attcat,
                       u16* __restrict__ NPt, float* __restrict__ q, int M, int NN){
    int l = threadIdx.x & 63, w = threadIdx.x >> 6;
    int rb = blockIdx.x * 64 + w * 16;
    int ar = rb + (l & 15); if (ar >= M) ar = M - 1;
    const u16* Ap = A + (size_t)ar * 128 + (l >> 4) * 8;
    short8v a0 = *(const short8v*)(Ap);
    short8v a1 = *(const short8v*)(Ap + 32);
    short8v a2 = *(const short8v*)(Ap + 64);
    short8v a3 = *(const short8v*)(Ap + 96);
    float qa[4] = {0.f, 0.f, 0.f, 0.f};
    int ntc = NN >> 4;
    for (int nt = 0; nt < ntc; ++nt){
        const u16* Wp = W + (size_t)(nt * 16 + (l & 15)) * 128 + (l >> 4) * 8;
        short8v b0 = *(const short8v*)(Wp);
        short8v b1 = *(const short8v*)(Wp + 32);
        short8v b2 = *(const short8v*)(Wp + 64);
        short8v b3 = *(const short8v*)(Wp + 96);
        float4v acc = {0.f, 0.f, 0.f, 0.f};
        acc = __builtin_amdgcn_mfma_f32_16x16x32_bf16(a0, b0, acc, 0, 0, 0);
        acc = __builtin_amdgcn_mfma_f32_16x16x32_bf16(a1, b1, acc, 0, 0, 0);
        acc = __builtin_amdgcn_mfma_f32_16x16x32_bf16(a2, b2, acc, 0, 0, 0);
        acc = __builtin_amdgcn_mfma_f32_16x16x32_bf16(a3, b3, acc, 0, 0, 0);
        int cc = nt * 16 + (l & 15);
        int seg = cc >> 7;
        int rr0 = rb + (l >> 4) * 4;
        #pragma unroll
        for (int r = 0; r < 4; ++r){
            int rr = rr0 + r;
            if (rr < M){
                if (seg < 4) NPt[(size_t)seg * SEG + (size_t)rr * 128 + (cc & 127)] = f2b(acc[r]);
                else         NPt[4 * SEG + (size_t)rr * 64 + (cc & 63)] = f2b(acc[r]);
            }
        }
        int g = nt >> 2;
        if (g < 8){
            float av = attcat[cc];
            #pragma unroll
            for (int r = 0; r < 4; ++r) qa[r] += av * acc[r];
            if ((nt & 3) == 3){
                #pragma unroll
                for (int r = 0; r < 4; ++r){
                    float s = qa[r];
                    s += __shfl_xor(s, 1); s += __shfl_xor(s, 2);
                    s += __shfl_xor(s, 4); s += __shfl_xor(s, 8);
                    if ((l & 15) == 0){
                        int rr = rr0 + r;
                        if (rr < M) q[(size_t)rr * 8 + g] = s;
                    }
                    qa[r] = 0.f;
                }
            }
        }
    }
}

// ---------------- CSR build: histogram / scan / static position records ----------------
__global__ void k_hist(const int* __restrict__ ei, u32* __restrict__ cnt){
    int e = blockIdx.x * blockDim.x + threadIdx.x;
    if (e >= E_EDGES) return;
    atomicAdd(&cnt[ei[E_EDGES + e]], 1u);          // in-aggregation key: col
    atomicAdd(&cnt[N_NODES + ei[e]], 1u);          // out-aggregation key: row
}

__launch_bounds__(1024)
__global__ void k_scan1(const u32* __restrict__ cnt, u32* __restrict__ off, u32* __restrict__ bsum){
    __shared__ u32 sh[1024];
    int t = threadIdx.x, b = blockIdx.x, idx = b * 1024 + t;
    u32 v = cnt[idx];
    sh[t] = v; __syncthreads();
    #pragma unroll
    for (int d = 1; d < 1024; d <<= 1){
        u32 add = (t >= d) ? sh[t - d] : 0;
        __syncthreads();
        sh[t] += add;
        __syncthreads();
    }
    off[idx] = sh[t] - v;                          // exclusive within block
    if (t == 1023) bsum[b] = sh[1023];
}

__global__ void k_scan2(u32* __restrict__ bsum){
    if (threadIdx.x == 0){
        u32 run = 0;
        for (int i = 0; i < SCAN_B; ++i){ u32 t = bsum[i]; bsum[i] = run; run += t; }
    }
}

__launch_bounds__(1024)
__global__ void k_scan3(u32* __restrict__ off, const u32* __restrict__ bsum){
    int idx = blockIdx.x * 1024 + threadIdx.x;
    off[idx] += bsum[blockIdx.x];
}

// static sorted-position records (once): Pso[p]=other|et<<20, Pss[p]=self
__global__ void k_pos(const int* __restrict__ ei, const int* __restrict__ ety,
                      u32* __restrict__ cur,
                      u32* __restrict__ Pso, u32* __restrict__ Pss){
    int e = blockIdx.x * blockDim.x + threadIdx.x;
    if (e >= E_EDGES) return;
    u32 row = (u32)ei[e], col = (u32)ei[E_EDGES + e];
    u32 etb = (u32)ety[e] << 20;
    u32 pI = atomicAdd(&cur[col], 1u);             // in-list keyed by col
    Pso[pI] = row | etb;  Pss[pI] = col;
    u32 pO = atomicAdd(&cur[N_NODES + row], 1u);   // out-list keyed by row
    Pso[pO] = col | etb;  Pss[pO] = row;
}

// ---------------- edge pass A (position space): exps per position, NO atomics ----------------
// exI[p] = (e_in_h0, e_in_h1); exO[p] = (e_out_h0, e_out_h1)
__global__ void k_edgeA(const u32* __restrict__ Pso, const u32* __restrict__ Pss,
                        const float* __restrict__ q,
                        const float* __restrict__ qgI, const float* __restrict__ qgO,
                        float2* __restrict__ exI, float2* __restrict__ exO){
    int p = blockIdx.x * blockDim.x + threadIdx.x;
    if (p >= 2 * E_EDGES) return;
    u32 so = Pso[p], self = Pss[p];
    u32 oth = so & 0xFFFFF, et = so >> 20;
    u32 row, col;
    if (p < E_EDGES){ row = oth; col = self; } else { row = self; col = oth; }
    const float* qr = q + (size_t)row * 8;
    const float* qc = q + (size_t)col * 8;
    float2 ri, ro;
    ri.x = expf(lrelu(qr[0] + qc[2] + qgI[(size_t)et * 2 + 0]));
    ri.y = expf(lrelu(qr[1] + qc[3] + qgI[(size_t)et * 2 + 1]));
    ro.x = expf(lrelu(qc[4] + qr[6] + qgO[(size_t)et * 2 + 0]));
    ro.y = expf(lrelu(qc[5] + qr[7] + qgO[(size_t)et * 2 + 1]));
    exI[p] = ri;
    exO[p] = ro;
}

// ---------------- denominators by CSR duality (no atomics), store reciprocals ----------------
__global__ void k_denom(const u32* __restrict__ off,
                        const float2* __restrict__ exI, const float2* __restrict__ exO,
                        float* __restrict__ rdI, float* __restrict__ rdO){
    int n = blockIdx.x * blockDim.x + threadIdx.x;
    if (n >= N_NODES) return;
    float s0 = 0.f, s1 = 0.f;
    for (u32 p = off[N_NODES + n]; p < off[N_NODES + n + 1]; ++p){
        float2 v = exI[p]; s0 += v.x; s1 += v.y;
    }
    rdI[(size_t)n * 2 + 0] = (s0 > 0.f) ? 1.f / s0 : 0.f;
    rdI[(size_t)n * 2 + 1] = (s1 > 0.f) ? 1.f / s1 : 0.f;
    float t0 = 0.f, t1 = 0.f;
    for (u32 p = off[n]; p < off[n + 1]; ++p){
        float2 v = exO[p]; t0 += v.x; t1 += v.y;
    }
    rdO[(size_t)n * 2 + 0] = (t0 > 0.f) ? 1.f / t0 : 0.f;
    rdO[(size_t)n * 2 + 1] = (t1 > 0.f) ? 1.f / t1 : 0.f;
}

// ---------------- fused gather-aggregate + node epilogue ----------------
__launch_bounds__(256)
__global__ void k_agg(const u32* __restrict__ off,
                      const u32* __restrict__ Pso,
                      const float2* __restrict__ exI, const float2* __restrict__ exO,
                      const u16* __restrict__ NPt,
                      const float* __restrict__ PgI, const float* __restrict__ PgO,
                      const float* __restrict__ rdI, const float* __restrict__ rdO,
                      int final_stage,
                      const u16* __restrict__ NPt1, const float* __restrict__ be,
                      u16* __restrict__ h1b, float* __restrict__ out){
    int wid = threadIdx.x >> 6, l = threadIdx.x & 63;
    int n = blockIdx.x * 4 + wid;
    if (n >= N_NODES) return;
    int h = l >> 5, d0 = l * 2;
    const u16* PaI = NPt;
    const u16* PbI = NPt + SEG;
    const u16* PaO = NPt + 2 * SEG;
    const u16* PbO = NPt + 3 * SEG;
    u32 pbi = *(const u32*)(PbI + (size_t)n * 128 + d0);
    u32 pbo = *(const u32*)(PbO + (size_t)n * 128 + d0);

    float a0 = 0.f, a1 = 0.f, sai = 0.f;
    {
        u32 s0 = off[n], deg = off[n + 1] - s0;
        for (u32 base = 0; base < deg; base += 64){
            u32 k = base + (u32)l;
            u32 so = 0u; float w0 = 0.f, w1 = 0.f;
            if (k < deg){
                u32 idx = s0 + k;
                so = __builtin_nontemporal_load(Pso + idx);
                const float* ep = (const float*)exI + (size_t)idx * 2;
                float e0 = __builtin_nontemporal_load(ep);
                float e1 = __builtin_nontemporal_load(ep + 1);
                u32 oth = so & 0xFFFFFu;
                float2 rd2 = *(const float2*)(rdI + (size_t)oth * 2);
                w0 = e0 * rd2.x; w1 = e1 * rd2.y;
            }
            int cnt = (int)((deg - base < 64u) ? (deg - base) : 64u);
            for (int c = 0; c < cnt; c += 8){
                float wj[8]; u32 pa[8]; float2 gv[8];
                #pragma unroll
                for (int j = 0; j < 8; ++j){
                    u32 s = __shfl(so, c + j);
                    float v0 = __shfl(w0, c + j);
                    float v1 = __shfl(w1, c + j);
                    u32 oth = s & 0xFFFFFu, et = s >> 20;
                    pa[j] = *(const u32*)(PaI + (size_t)oth * 128 + d0);
                    gv[j] = *(const float2*)(PgI + (size_t)et * 128 + d0);
                    wj[j] = h ? v1 : v0;
                }
                #pragma unroll
                for (int j = 0; j < 8; ++j){
                    a0 += wj[j] * (bl(pa[j]) + gv[j].x);
                    a1 += wj[j] * (bh(pa[j]) + gv[j].y);
                    sai += wj[j];
                }
            }
        }
    }
    a0 += sai * bl(pbi);
    a1 += sai * bh(pbi);

    float b0 = 0.f, b1 = 0.f, sao = 0.f;
    {
        u32 s0 = off[N_NODES + n], deg = off[N_NODES + n + 1] - s0;
        for (u32 base = 0; base < deg; base += 64){
            u32 k = base + (u32)l;
            u32 so = 0u; float w0 = 0.f, w1 = 0.f;
            if (k < deg){
                u32 idx = s0 + k;
                so = __builtin_nontemporal_load(Pso + idx);
                const float* ep = (const float*)exO + (size_t)idx * 2;
                float e0 = __builtin_nontemporal_load(ep);
                float e1 = __builtin_nontemporal_load(ep + 1);
                u32 oth = so & 0xFFFFFu;
                float2 rd2 = *(const float2*)(rdO + (size_t)oth * 2);
                w0 = e0 * rd2.x; w1 = e1 * rd2.y;
            }
            int cnt = (int)((deg - base < 64u) ? (deg - base) : 64u);
            for (int c = 0; c < cnt; c += 8){
                float wj[8]; u32 pa[8]; float2 gv[8];
                #pragma unroll
                for (int j = 0; j < 8; ++j){
                    u32 s = __shfl(so, c + j);
                    float v0 = __shfl(w0, c + j);
                    float v1 = __shfl(w1, c + j);
                    u32 oth = s & 0xFFFFFu, et = s >> 20;
                    pa[j] = *(const u32*)(PaO + (size_t)oth * 128 + d0);
                    gv[j] = *(const float2*)(PgO + (size_t)et * 128 + d0);
                    wj[j] = h ? v1 : v0;
                }
                #pragma unroll
                for (int j = 0; j < 8; ++j){
                    b0 += wj[j] * (bl(pa[j]) + gv[j].x);
                    b1 += wj[j] * (bh(pa[j]) + gv[j].y);
                    sao += wj[j];
                }
            }
        }
    }
    b0 += sao * bl(pbo);
    b1 += sao * bh(pbo);

    float vx = lrelu(0.5f * (a0 + b0));
    float vy = lrelu(0.5f * (a1 + b1));
    float ss = vx * vx + vy * vy;
    #pragma unroll
    for (int m = 16; m; m >>= 1) ss += __shfl_xor(ss, m);    // per-head (32-lane) reduce
    float s2 = 1.f / fmaxf(sqrtf(ss), 1e-12f);
    if (!final_stage){
        *(u32*)(h1b + (size_t)n * 128 + d0) = pk2(vx * s2, vy * s2);
    } else {
        float h20 = vx * s2, h21 = vy * s2;
        int o0 = d0 & 63;
        u32 ue = *(const u32*)(NPt1 + 4 * SEG + (size_t)n * 64 + o0);
        float hp0 = bl(ue) + be[o0] + h20;
        float hp1 = bh(ue) + be[o0 + 1] + h21;
        float st = hp0 * hp0 + hp1 * hp1;
        #pragma unroll
        for (int m = 32; m; m >>= 1) st += __shfl_xor(st, m); // full 128-dim norm
        float s = 1.f / fmaxf(sqrtf(st), 1e-12f);
        float2 o; o.x = hp0 * s; o.y = hp1 * s;
        *(float2*)(out + (size_t)n * 128 + d0) = o;
    }
}

extern "C" void kernel_launch(void* const* d_in, const int* in_sizes, int n_in,
                              void* d_out, int out_size, void* d_ws, size_t ws_size,
                              hipStream_t stream){
    const float* x   = (const float*)d_in[0];
    const float* g   = (const float*)d_in[1];
    const int*   ei  = (const int*)d_in[2];
    const int*   ety = (const int*)d_in[3];
    const float* W1i = (const float*)d_in[4];
    const float* b1i = (const float*)d_in[5];
    const float* a1i = (const float*)d_in[6];
    const float* W1o = (const float*)d_in[7];
    const float* b1o = (const float*)d_in[8];
    const float* a1o = (const float*)d_in[9];
    const float* W2i = (const float*)d_in[10];
    const float* b2i = (const float*)d_in[11];
    const float* a2i = (const float*)d_in[12];
    const float* W2o = (const float*)d_in[13];
    const float* b2o = (const float*)d_in[14];
    const float* a2o = (const float*)d_in[15];
    const float* We  = (const float*)d_in[16];
    const float* be  = (const float*)d_in[17];
    const float* Wr  = (const float*)d_in[18];
    const float* br  = (const float*)d_in[19];
    float* out = (float*)d_out;

    char* ws = (char*)d_ws;
    size_t off_b = 0;
    auto carve = [&](size_t bytes) -> char* {
        char* p = ws + off_b;
        off_b += (bytes + 255) & ~(size_t)255;
        return p;
    };
    u16*    xnb   = (u16*)carve((size_t)N_NODES * 128 * 2);
    u16*    wc1   = (u16*)carve((size_t)576 * 128 * 2);
    u16*    wc2   = (u16*)carve((size_t)512 * 128 * 2);
    float*  attct = (float*)carve((size_t)1024 * 4);
    u16*    NPt1  = (u16*)carve((SEG * 4 + (size_t)N_NODES * 64) * 2);  // 4 segs + entity
    u16*    NPt2  = (u16*)carve(SEG * 4 * 2);
    u16*    h1b   = (u16*)carve((size_t)N_NODES * 128 * 2);
    float*  q     = (float*)carve((size_t)N_NODES * 8 * 4);
    float*  Pg    = (float*)carve((size_t)4 * R_REL * 128 * 4);
    float*  qg    = (float*)carve((size_t)4 * R_REL * 2 * 4);
    u32*    cnt   = (u32*)carve((size_t)SCAN_B * 1024 * 4);    // zeroed, padded
    u32*    offA  = (u32*)carve((size_t)SCAN_B * 1024 * 4);    // exclusive scan
    u32*    cur   = (u32*)carve((size_t)NKEYS * 4);            // position cursors
    u32*    bsum  = (u32*)carve((size_t)SCAN_B * 4);
    u32*    Pso   = (u32*)carve((size_t)2 * E_EDGES * 4);      // other|et<<20 (static)
    u32*    Pss   = (u32*)carve((size_t)2 * E_EDGES * 4);      // self (static)
    float2* exI   = (float2*)carve((size_t)2 * E_EDGES * 8);   // per-stage in-dir exps
    float2* exO   = (float2*)carve((size_t)2 * E_EDGES * 8);   // per-stage out-dir exps
    float*  rdI   = (float*)carve((size_t)N_NODES * 2 * 4);    // reciprocal denoms
    float*  rdO   = (float*)carve((size_t)N_NODES * 2 * 4);

    // ---------------- stage 0: prep (CSR positions + tables + GEMM input) ----------------
    hipMemsetAsync(cnt, 0, (size_t)SCAN_B * 1024 * 4, stream);
    k_hist<<<1563, 256, 0, stream>>>(ei, cnt);
    k_scan1<<<SCAN_B, 1024, 0, stream>>>(cnt, offA, bsum);
    k_scan2<<<1, 64, 0, stream>>>(bsum);
    k_scan3<<<SCAN_B, 1024, 0, stream>>>(offA, bsum);
    hipMemcpyAsync(cur, offA, (size_t)NKEYS * 4, hipMemcpyDeviceToDevice, stream);
    k_pos<<<1563, 256, 0, stream>>>(ei, ety, cur, Pso, Pss);

    k_norm_x<<<12500, 256, 0, stream>>>(x, xnb);
    k_build_wcat<<<548, 256, 0, stream>>>(W1i, W1o, W2i, W2o, We,
                                          a1i, a1o, a2i, a2o, wc1, wc2, attct);
    k_pg<<<2000, 128, 0, stream>>>(g, W1i, W1o, W2i, W2o, b1i, b1o, b2i, b2o,
                                   a1i, a1o, a2i, a2o, Pg, qg);
    k_gprime<<<500, 128, 0, stream>>>(g, Wr, br, out);

    // ---------------- stage 1 ----------------
    k_gemm<<<782, 256, 0, stream>>>(xnb, wc1, attct, NPt1, q, N_NODES, 576);
    k_edgeA<<<3125, 256, 0, stream>>>(Pso, Pss, q, qg, qg + R_REL * 2, exI, exO);
    k_denom<<<196, 256, 0, stream>>>(offA, exI, exO, rdI, rdO);
    k_agg<<<12500, 256, 0, stream>>>(offA, Pso, exI, exO, NPt1, Pg, Pg + R_REL * 128,
                                     rdI, rdO, 0, NPt1, be, h1b, out);

    // ---------------- stage 2 ----------------
    k_gemm<<<782, 256, 0, stream>>>(h1b, wc2, attct + 512, NPt2, q, N_NODES, 512);
    k_edgeA<<<3125, 256, 0, stream>>>(Pso, Pss, q, qg + 2 * R_REL * 2, qg + 3 * R_REL * 2,
                                      exI, exO);
    k_denom<<<196, 256, 0, stream>>>(offA, exI, exO, rdI, rdO);
    k_agg<<<12500, 256, 0, stream>>>(offA, Pso, exI, exO, NPt2, Pg + 2 * R_REL * 128,
                                     Pg + 3 * R_REL * 128, rdI, rdO, 1, NPt1, be, h1b, out);
}

// Round 12
// 425.538 us; speedup vs baseline: 1.0840x; 1.0278x over previous
//
#include <hip/hip_runtime.h>

typedef unsigned short u16;
typedef unsigned int u32;
typedef short short8v __attribute__((ext_vector_type(8)));
typedef float float4v __attribute__((ext_vector_type(4)));

#define N_NODES 50000
#define E_EDGES 400000
#define R_REL   500
#define NKEYS   100000          // cntI[50000] | cntO[50000]
#define SCAN_B  98              // 98*1024 = 100352 >= NKEYS
#define SEG     ((size_t)N_NODES * 128)

__device__ __forceinline__ float bl(u32 u){ return __uint_as_float(u << 16); }
__device__ __forceinline__ float bh(u32 u){ return __uint_as_float(u & 0xffff0000u); }
__device__ __forceinline__ u16 f2b(float f){
    u32 u = __float_as_uint(f);
    return (u16)((u + 0x7fffu + ((u >> 16) & 1u)) >> 16);
}
__device__ __forceinline__ u32 pk2(float a, float b){ return (u32)f2b(a) | ((u32)f2b(b) << 16); }
__device__ __forceinline__ float lrelu(float x){ return x > 0.f ? x : 0.01f * x; }

// ---------------- normalize x -> bf16 padded [N,128] ----------------
__global__ void k_norm_x(const float* __restrict__ x, u16* __restrict__ xnb){
    int wid = threadIdx.x >> 6, l = threadIdx.x & 63;
    int n = blockIdx.x * 4 + wid;
    if (n >= N_NODES) return;
    float v0 = x[(size_t)n * 100 + l];
    float v1 = (l + 64 < 100) ? x[(size_t)n * 100 + 64 + l] : 0.f;
    float ss = v0 * v0 + v1 * v1;
    #pragma unroll
    for (int m = 32; m; m >>= 1) ss += __shfl_xor(ss, m);
    float s = 1.f / fmaxf(sqrtf(ss), 1e-12f);
    xnb[(size_t)n * 128 + l] = f2b(v0 * s);
    xnb[(size_t)n * 128 + 64 + l] = (l + 64 < 100) ? f2b(v1 * s) : (u16)0;
}

// ---------------- build concatenated weights (bf16) + attcat tables ----------------
__global__ void k_build_wcat(const float* __restrict__ W1i, const float* __restrict__ W1o,
                             const float* __restrict__ W2i, const float* __restrict__ W2o,
                             const float* __restrict__ We,
                             const float* __restrict__ a1i, const float* __restrict__ a1o,
                             const float* __restrict__ a2i, const float* __restrict__ a2o,
                             u16* __restrict__ wc1, u16* __restrict__ wc2,
                             float* __restrict__ attcat){
    int idx = blockIdx.x * blockDim.x + threadIdx.x;
    if (idx < 576 * 128){
        int r = idx >> 7, k = idx & 127;
        float v = 0.f;
        if (r < 512){
            int seg = r >> 7, rr = r & 127;
            const float* W = (seg < 2) ? W1i : W1o;
            int off = (seg & 1) ? 100 : 0;
            if (k < 100) v = W[(size_t)rr * 300 + off + k];
        } else {
            int rr = r - 512;
            if (k < 100) v = We[(size_t)rr * 100 + k];
        }
        wc1[idx] = f2b(v);
    } else if (idx < 576 * 128 + 512 * 128){
        int j = idx - 576 * 128;
        int r = j >> 7, k = j & 127;
        int seg = r >> 7, rr = r & 127;
        const float* W = (seg < 2) ? W2i : W2o;
        int off = (seg & 1) ? 128 : 0;
        wc2[j] = f2b(W[(size_t)rr * 356 + off + k]);
    } else if (idx < 576 * 128 + 512 * 128 + 1024){
        int j = idx - (576 * 128 + 512 * 128);
        int s = j >> 9, cc = j & 511;
        const float* a = s ? ((cc < 256) ? a2i : a2o) : ((cc < 256) ? a1i : a1o);
        attcat[j] = a[cc & 127];
    }
}

// ---------------- relation tables ----------------
__global__ void k_pg(const float* __restrict__ g,
                     const float* __restrict__ W1i, const float* __restrict__ W1o,
                     const float* __restrict__ W2i, const float* __restrict__ W2o,
                     const float* __restrict__ b1i, const float* __restrict__ b1o,
                     const float* __restrict__ b2i, const float* __restrict__ b2o,
                     const float* __restrict__ a1i, const float* __restrict__ a1o,
                     const float* __restrict__ a2i, const float* __restrict__ a2o,
                     float* __restrict__ Pg, float* __restrict__ qg){
    int bid = blockIdx.x;
    int r = bid >> 2, t = bid & 3;
    const float *W, *b, *att; int ld, off;
    if (t == 0){ W = W1i; ld = 300; off = 200; b = b1i; att = a1i; }
    else if (t == 1){ W = W1o; ld = 300; off = 200; b = b1o; att = a1o; }
    else if (t == 2){ W = W2i; ld = 356; off = 256; b = b2i; att = a2i; }
    else { W = W2o; ld = 356; off = 256; b = b2o; att = a2o; }
    __shared__ float gs[100];
    __shared__ float red[128];
    int j = threadIdx.x; // 128 threads
    if (j < 100) gs[j] = g[(size_t)r * 100 + j];
    __syncthreads();
    float acc = b[j];
    #pragma unroll 4
    for (int k = 0; k < 100; ++k) acc += gs[k] * W[(size_t)j * ld + off + k];
    Pg[((size_t)t * R_REL + r) * 128 + j] = acc;
    red[j] = att[j] * acc;
    __syncthreads();
    if (j < 2){
        float s = 0.f;
        for (int k = 0; k < 64; ++k) s += red[j * 64 + k];
        qg[((size_t)t * R_REL + r) * 2 + j] = s;
    }
}

// ---------------- g_prime = g @ Wr^T + br -> out (f32) ----------------
__global__ void k_gprime(const float* __restrict__ g, const float* __restrict__ Wr,
                         const float* __restrict__ br, float* __restrict__ out){
    int r = blockIdx.x, j = threadIdx.x; // 128 threads
    __shared__ float gs[100];
    if (j < 100) gs[j] = g[(size_t)r * 100 + j];
    __syncthreads();
    float acc = br[j];
    #pragma unroll 4
    for (int k = 0; k < 100; ++k) acc += gs[k] * Wr[(size_t)j * 100 + k];
    out[(size_t)N_NODES * 128 + (size_t)r * 128 + j] = acc;
}

// ---------------- node GEMM: column-group split + LDS-staged coalesced stores ----------------
// blockIdx.y = 128-col group. Packed layout: NPt[seg][row][0..127] rows contiguous, so a
// wave's 16x128 tile is 4KB contiguous -> 4 x 1KB dwordx4 wave stores via LDS transpose.
__launch_bounds__(256)
__global__ void k_gemm(const u16* __restrict__ A, const u16* __restrict__ W,
                       const float* __restrict__ attcat,
                       u16* __restrict__ NPt, float* __restrict__ q, int M, int NN){
    __shared__ __align__(16) char lds[4 * 16 * 272];
    int l = threadIdx.x & 63, w = threadIdx.x >> 6;
    int rb = blockIdx.x * 64 + w * 16;
    int grp = blockIdx.y;
    int cb = grp * 128;
    int ncols = NN - cb; if (ncols > 128) ncols = 128;
    int tiles = ncols >> 4;
    int rowW = (ncols == 128) ? 128 : 64;       // u16 per output row in this group
    int pitch = rowW * 2 + 16;                  // 272 or 144 (16B aligned)
    char* lw = lds + w * 16 * pitch;

    int ar = rb + (l & 15); if (ar >= M) ar = M - 1;
    const u16* Ap = A + (size_t)ar * 128 + (l >> 4) * 8;
    short8v a0 = *(const short8v*)(Ap);
    short8v a1 = *(const short8v*)(Ap + 32);
    short8v a2 = *(const short8v*)(Ap + 64);
    short8v a3 = *(const short8v*)(Ap + 96);
    float qa[4] = {0.f, 0.f, 0.f, 0.f};
    bool doq = (cb < 512);
    int rloc0 = (l >> 4) * 4;
    for (int t = 0; t < tiles; ++t){
        int cc = cb + t * 16 + (l & 15);
        const u16* Wp = W + (size_t)cc * 128 + (l >> 4) * 8;
        short8v b0 = *(const short8v*)(Wp);
        short8v b1 = *(const short8v*)(Wp + 32);
        short8v b2 = *(const short8v*)(Wp + 64);
        short8v b3 = *(const short8v*)(Wp + 96);
        float4v acc = {0.f, 0.f, 0.f, 0.f};
        acc = __builtin_amdgcn_mfma_f32_16x16x32_bf16(a0, b0, acc, 0, 0, 0);
        acc = __builtin_amdgcn_mfma_f32_16x16x32_bf16(a1, b1, acc, 0, 0, 0);
        acc = __builtin_amdgcn_mfma_f32_16x16x32_bf16(a2, b2, acc, 0, 0, 0);
        acc = __builtin_amdgcn_mfma_f32_16x16x32_bf16(a3, b3, acc, 0, 0, 0);
        int lcol = t * 16 + (l & 15);
        #pragma unroll
        for (int r = 0; r < 4; ++r)
            *(u16*)(lw + (size_t)(rloc0 + r) * pitch + lcol * 2) = f2b(acc[r]);
        if (doq){
            float av = attcat[cc];
            #pragma unroll
            for (int r = 0; r < 4; ++r) qa[r] += av * acc[r];
            if ((t & 3) == 3){
                int g = (cb >> 6) + (t >> 2);
                #pragma unroll
                for (int r = 0; r < 4; ++r){
                    float s = qa[r];
                    s += __shfl_xor(s, 1); s += __shfl_xor(s, 2);
                    s += __shfl_xor(s, 4); s += __shfl_xor(s, 8);
                    if ((l & 15) == 0){
                        int rr = rb + rloc0 + r;
                        if (rr < M) q[(size_t)rr * 8 + g] = s;
                    }
                    qa[r] = 0.f;
                }
            }
        }
    }
    __syncthreads();
    // coalesced store: wave tile (16 rows x rowW u16) is contiguous in global
    u16* gb = (rowW == 128) ? (NPt + (size_t)grp * SEG + (size_t)rb * 128)
                            : (NPt + 4 * SEG + (size_t)rb * 64);
    int chunks = (rowW == 128) ? 4 : 2;        // 16*rowW*2 / 1024
    for (int i = 0; i < chunks; ++i){
        int u = i * 512 + l * 8;               // u16 linear offset within tile
        int rloc = (rowW == 128) ? (u >> 7) : (u >> 6);
        int c    = (rowW == 128) ? (u & 127) : (u & 63);
        if (rb + rloc < M){
            short8v v = *(const short8v*)(lw + (size_t)rloc * pitch + c * 2);
            *(short8v*)(gb + u) = v;
        }
    }
}

// ---------------- CSR build: histogram / scan / static position records ----------------
__global__ void k_hist(const int* __restrict__ ei, u32* __restrict__ cnt){
    int e = blockIdx.x * blockDim.x + threadIdx.x;
    if (e >= E_EDGES) return;
    atomicAdd(&cnt[ei[E_EDGES + e]], 1u);          // in-aggregation key: col
    atomicAdd(&cnt[N_NODES + ei[e]], 1u);          // out-aggregation key: row
}

__launch_bounds__(1024)
__global__ void k_scan1(const u32* __restrict__ cnt, u32* __restrict__ off, u32* __restrict__ bsum){
    __shared__ u32 sh[1024];
    int t = threadIdx.x, b = blockIdx.x, idx = b * 1024 + t;
    u32 v = cnt[idx];
    sh[t] = v; __syncthreads();
    #pragma unroll
    for (int d = 1; d < 1024; d <<= 1){
        u32 add = (t >= d) ? sh[t - d] : 0;
        __syncthreads();
        sh[t] += add;
        __syncthreads();
    }
    off[idx] = sh[t] - v;                          // exclusive within block
    if (t == 1023) bsum[b] = sh[1023];
}

__global__ void k_scan2(u32* __restrict__ bsum){
    if (threadIdx.x == 0){
        u32 run = 0;
        for (int i = 0; i < SCAN_B; ++i){ u32 t = bsum[i]; bsum[i] = run; run += t; }
    }
}

__launch_bounds__(1024)
__global__ void k_scan3(u32* __restrict__ off, const u32* __restrict__ bsum){
    int idx = blockIdx.x * 1024 + threadIdx.x;
    off[idx] += bsum[blockIdx.x];
}

// static sorted-position records (once): Pso[p]=other|et<<20, Pss[p]=self
__global__ void k_pos(const int* __restrict__ ei, const int* __restrict__ ety,
                      u32* __restrict__ cur,
                      u32* __restrict__ Pso, u32* __restrict__ Pss){
    int e = blockIdx.x * blockDim.x + threadIdx.x;
    if (e >= E_EDGES) return;
    u32 row = (u32)ei[e], col = (u32)ei[E_EDGES + e];
    u32 etb = (u32)ety[e] << 20;
    u32 pI = atomicAdd(&cur[col], 1u);             // in-list keyed by col
    Pso[pI] = row | etb;  Pss[pI] = col;
    u32 pO = atomicAdd(&cur[N_NODES + row], 1u);   // out-list keyed by row
    Pso[pO] = col | etb;  Pss[pO] = row;
}

// ---------------- edge pass A (position space): exps per position, NO atomics ----------------
__global__ void k_edgeA(const u32* __restrict__ Pso, const u32* __restrict__ Pss,
                        const float* __restrict__ q,
                        const float* __restrict__ qgI, const float* __restrict__ qgO,
                        float2* __restrict__ exI, float2* __restrict__ exO){
    int p = blockIdx.x * blockDim.x + threadIdx.x;
    if (p >= 2 * E_EDGES) return;
    u32 so = Pso[p], self = Pss[p];
    u32 oth = so & 0xFFFFF, et = so >> 20;
    u32 row, col;
    if (p < E_EDGES){ row = oth; col = self; } else { row = self; col = oth; }
    const float* qr = q + (size_t)row * 8;
    const float* qc = q + (size_t)col * 8;
    float2 ri, ro;
    ri.x = expf(lrelu(qr[0] + qc[2] + qgI[(size_t)et * 2 + 0]));
    ri.y = expf(lrelu(qr[1] + qc[3] + qgI[(size_t)et * 2 + 1]));
    ro.x = expf(lrelu(qc[4] + qr[6] + qgO[(size_t)et * 2 + 0]));
    ro.y = expf(lrelu(qc[5] + qr[7] + qgO[(size_t)et * 2 + 1]));
    exI[p] = ri;
    exO[p] = ro;
}

// ---------------- denominators by CSR duality (no atomics), store reciprocals ----------------
__global__ void k_denom(const u32* __restrict__ off,
                        const float2* __restrict__ exI, const float2* __restrict__ exO,
                        float* __restrict__ rdI, float* __restrict__ rdO){
    int n = blockIdx.x * blockDim.x + threadIdx.x;
    if (n >= N_NODES) return;
    float s0 = 0.f, s1 = 0.f;
    for (u32 p = off[N_NODES + n]; p < off[N_NODES + n + 1]; ++p){
        float2 v = exI[p]; s0 += v.x; s1 += v.y;
    }
    rdI[(size_t)n * 2 + 0] = (s0 > 0.f) ? 1.f / s0 : 0.f;
    rdI[(size_t)n * 2 + 1] = (s1 > 0.f) ? 1.f / s1 : 0.f;
    float t0 = 0.f, t1 = 0.f;
    for (u32 p = off[n]; p < off[n + 1]; ++p){
        float2 v = exO[p]; t0 += v.x; t1 += v.y;
    }
    rdO[(size_t)n * 2 + 0] = (t0 > 0.f) ? 1.f / t0 : 0.f;
    rdO[(size_t)n * 2 + 1] = (t1 > 0.f) ? 1.f / t1 : 0.f;
}

// ---------------- fused gather-aggregate + node epilogue ----------------
__launch_bounds__(256)
__global__ void k_agg(const u32* __restrict__ off,
                      const u32* __restrict__ Pso,
                      const float2* __restrict__ exI, const float2* __restrict__ exO,
                      const u16* __restrict__ NPt,
                      const float* __restrict__ PgI, const float* __restrict__ PgO,
                      const float* __restrict__ rdI, const float* __restrict__ rdO,
                      int final_stage,
                      const u16* __restrict__ NPt1, const float* __restrict__ be,
                      u16* __restrict__ h1b, float* __restrict__ out){
    int wid = threadIdx.x >> 6, l = threadIdx.x & 63;
    int n = blockIdx.x * 4 + wid;
    if (n >= N_NODES) return;
    int h = l >> 5, d0 = l * 2;
    const u16* PaI = NPt;
    const u16* PbI = NPt + SEG;
    const u16* PaO = NPt + 2 * SEG;
    const u16* PbO = NPt + 3 * SEG;
    u32 pbi = *(const u32*)(PbI + (size_t)n * 128 + d0);
    u32 pbo = *(const u32*)(PbO + (size_t)n * 128 + d0);

    float a0 = 0.f, a1 = 0.f, sai = 0.f;
    {
        u32 s0 = off[n], deg = off[n + 1] - s0;
        for (u32 base = 0; base < deg; base += 64){
            u32 k = base + (u32)l;
            u32 so = 0u; float w0 = 0.f, w1 = 0.f;
            if (k < deg){
                u32 idx = s0 + k;
                so = __builtin_nontemporal_load(Pso + idx);
                const float* ep = (const float*)exI + (size_t)idx * 2;
                float e0 = __builtin_nontemporal_load(ep);
                float e1 = __builtin_nontemporal_load(ep + 1);
                u32 oth = so & 0xFFFFFu;
                float2 rd2 = *(const float2*)(rdI + (size_t)oth * 2);
                w0 = e0 * rd2.x; w1 = e1 * rd2.y;
            }
            int cnt = (int)((deg - base < 64u) ? (deg - base) : 64u);
            for (int c = 0; c < cnt; c += 8){
                float wj[8]; u32 pa[8]; float2 gv[8];
                #pragma unroll
                for (int j = 0; j < 8; ++j){
                    u32 s = __shfl(so, c + j);
                    float v0 = __shfl(w0, c + j);
                    float v1 = __shfl(w1, c + j);
                    u32 oth = s & 0xFFFFFu, et = s >> 20;
                    pa[j] = *(const u32*)(PaI + (size_t)oth * 128 + d0);
                    gv[j] = *(const float2*)(PgI + (size_t)et * 128 + d0);
                    wj[j] = h ? v1 : v0;
                }
                #pragma unroll
                for (int j = 0; j < 8; ++j){
                    a0 += wj[j] * (bl(pa[j]) + gv[j].x);
                    a1 += wj[j] * (bh(pa[j]) + gv[j].y);
                    sai += wj[j];
                }
            }
        }
    }
    a0 += sai * bl(pbi);
    a1 += sai * bh(pbi);

    float b0 = 0.f, b1 = 0.f, sao = 0.f;
    {
        u32 s0 = off[N_NODES + n], deg = off[N_NODES + n + 1] - s0;
        for (u32 base = 0; base < deg; base += 64){
            u32 k = base + (u32)l;
            u32 so = 0u; float w0 = 0.f, w1 = 0.f;
            if (k < deg){
                u32 idx = s0 + k;
                so = __builtin_nontemporal_load(Pso + idx);
                const float* ep = (const float*)exO + (size_t)idx * 2;
                float e0 = __builtin_nontemporal_load(ep);
                float e1 = __builtin_nontemporal_load(ep + 1);
                u32 oth = so & 0xFFFFFu;
                float2 rd2 = *(const float2*)(rdO + (size_t)oth * 2);
                w0 = e0 * rd2.x; w1 = e1 * rd2.y;
            }
            int cnt = (int)((deg - base < 64u) ? (deg - base) : 64u);
            for (int c = 0; c < cnt; c += 8){
                float wj[8]; u32 pa[8]; float2 gv[8];
                #pragma unroll
                for (int j = 0; j < 8; ++j){
                    u32 s = __shfl(so, c + j);
                    float v0 = __shfl(w0, c + j);
                    float v1 = __shfl(w1, c + j);
                    u32 oth = s & 0xFFFFFu, et = s >> 20;
                    pa[j] = *(const u32*)(PaO + (size_t)oth * 128 + d0);
                    gv[j] = *(const float2*)(PgO + (size_t)et * 128 + d0);
                    wj[j] = h ? v1 : v0;
                }
                #pragma unroll
                for (int j = 0; j < 8; ++j){
                    b0 += wj[j] * (bl(pa[j]) + gv[j].x);
                    b1 += wj[j] * (bh(pa[j]) + gv[j].y);
                    sao += wj[j];
                }
            }
        }
    }
    b0 += sao * bl(pbo);
    b1 += sao * bh(pbo);

    float vx = lrelu(0.5f * (a0 + b0));
    float vy = lrelu(0.5f * (a1 + b1));
    float ss = vx * vx + vy * vy;
    #pragma unroll
    for (int m = 16; m; m >>= 1) ss += __shfl_xor(ss, m);    // per-head (32-lane) reduce
    float s2 = 1.f / fmaxf(sqrtf(ss), 1e-12f);
    if (!final_stage){
        *(u32*)(h1b + (size_t)n * 128 + d0) = pk2(vx * s2, vy * s2);
    } else {
        float h20 = vx * s2, h21 = vy * s2;
        int o0 = d0 & 63;
        u32 ue = *(const u32*)(NPt1 + 4 * SEG + (size_t)n * 64 + o0);
        float hp0 = bl(ue) + be[o0] + h20;
        float hp1 = bh(ue) + be[o0 + 1] + h21;
        float st = hp0 * hp0 + hp1 * hp1;
        #pragma unroll
        for (int m = 32; m; m >>= 1) st += __shfl_xor(st, m); // full 128-dim norm
        float s = 1.f / fmaxf(sqrtf(st), 1e-12f);
        float2 o; o.x = hp0 * s; o.y = hp1 * s;
        *(float2*)(out + (size_t)n * 128 + d0) = o;
    }
}

extern "C" void kernel_launch(void* const* d_in, const int* in_sizes, int n_in,
                              void* d_out, int out_size, void* d_ws, size_t ws_size,
                              hipStream_t stream){
    const float* x   = (const float*)d_in[0];
    const float* g   = (const float*)d_in[1];
    const int*   ei  = (const int*)d_in[2];
    const int*   ety = (const int*)d_in[3];
    const float* W1i = (const float*)d_in[4];
    const float* b1i = (const float*)d_in[5];
    const float* a1i = (const float*)d_in[6];
    const float* W1o = (const float*)d_in[7];
    const float* b1o = (const float*)d_in[8];
    const float* a1o = (const float*)d_in[9];
    const float* W2i = (const float*)d_in[10];
    const float* b2i = (const float*)d_in[11];
    const float* a2i = (const float*)d_in[12];
    const float* W2o = (const float*)d_in[13];
    const float* b2o = (const float*)d_in[14];
    const float* a2o = (const float*)d_in[15];
    const float* We  = (const float*)d_in[16];
    const float* be  = (const float*)d_in[17];
    const float* Wr  = (const float*)d_in[18];
    const float* br  = (const float*)d_in[19];
    float* out = (float*)d_out;

    char* ws = (char*)d_ws;
    size_t off_b = 0;
    auto carve = [&](size_t bytes) -> char* {
        char* p = ws + off_b;
        off_b += (bytes + 255) & ~(size_t)255;
        return p;
    };
    u16*    xnb   = (u16*)carve((size_t)N_NODES * 128 * 2);
    u16*    wc1   = (u16*)carve((size_t)576 * 128 * 2);
    u16*    wc2   = (u16*)carve((size_t)512 * 128 * 2);
    float*  attct = (float*)carve((size_t)1024 * 4);
    u16*    NPt1  = (u16*)carve((SEG * 4 + (size_t)N_NODES * 64) * 2);  // 4 segs + entity
    u16*    NPt2  = (u16*)carve(SEG * 4 * 2);
    u16*    h1b   = (u16*)carve((size_t)N_NODES * 128 * 2);
    float*  q     = (float*)carve((size_t)N_NODES * 8 * 4);
    float*  Pg    = (float*)carve((size_t)4 * R_REL * 128 * 4);
    float*  qg    = (float*)carve((size_t)4 * R_REL * 2 * 4);
    u32*    cnt   = (u32*)carve((size_t)SCAN_B * 1024 * 4);    // zeroed, padded
    u32*    offA  = (u32*)carve((size_t)SCAN_B * 1024 * 4);    // exclusive scan
    u32*    cur   = (u32*)carve((size_t)NKEYS * 4);            // position cursors
    u32*    bsum  = (u32*)carve((size_t)SCAN_B * 4);
    u32*    Pso   = (u32*)carve((size_t)2 * E_EDGES * 4);      // other|et<<20 (static)
    u32*    Pss   = (u32*)carve((size_t)2 * E_EDGES * 4);      // self (static)
    float2* exI   = (float2*)carve((size_t)2 * E_EDGES * 8);   // per-stage in-dir exps
    float2* exO   = (float2*)carve((size_t)2 * E_EDGES * 8);   // per-stage out-dir exps
    float*  rdI   = (float*)carve((size_t)N_NODES * 2 * 4);    // reciprocal denoms
    float*  rdO   = (float*)carve((size_t)N_NODES * 2 * 4);

    // ---------------- stage 0: prep (CSR positions + tables + GEMM input) ----------------
    hipMemsetAsync(cnt, 0, (size_t)SCAN_B * 1024 * 4, stream);
    k_hist<<<1563, 256, 0, stream>>>(ei, cnt);
    k_scan1<<<SCAN_B, 1024, 0, stream>>>(cnt, offA, bsum);
    k_scan2<<<1, 64, 0, stream>>>(bsum);
    k_scan3<<<SCAN_B, 1024, 0, stream>>>(offA, bsum);
    hipMemcpyAsync(cur, offA, (size_t)NKEYS * 4, hipMemcpyDeviceToDevice, stream);
    k_pos<<<1563, 256, 0, stream>>>(ei, ety, cur, Pso, Pss);

    k_norm_x<<<12500, 256, 0, stream>>>(x, xnb);
    k_build_wcat<<<548, 256, 0, stream>>>(W1i, W1o, W2i, W2o, We,
                                          a1i, a1o, a2i, a2o, wc1, wc2, attct);
    k_pg<<<2000, 128, 0, stream>>>(g, W1i, W1o, W2i, W2o, b1i, b1o, b2i, b2o,
                                   a1i, a1o, a2i, a2o, Pg, qg);
    k_gprime<<<500, 128, 0, stream>>>(g, Wr, br, out);

    // ---------------- stage 1 ----------------
    k_gemm<<<dim3(782, 5), 256, 0, stream>>>(xnb, wc1, attct, NPt1, q, N_NODES, 576);
    k_edgeA<<<3125, 256, 0, stream>>>(Pso, Pss, q, qg, qg + R_REL * 2, exI, exO);
    k_denom<<<196, 256, 0, stream>>>(offA, exI, exO, rdI, rdO);
    k_agg<<<12500, 256, 0, stream>>>(offA, Pso, exI, exO, NPt1, Pg, Pg + R_REL * 128,
                                     rdI, rdO, 0, NPt1, be, h1b, out);

    // ---------------- stage 2 ----------------
    k_gemm<<<dim3(782, 4), 256, 0, stream>>>(h1b, wc2, attct + 512, NPt2, q, N_NODES, 512);
    k_edgeA<<<3125, 256, 0, stream>>>(Pso, Pss, q, qg + 2 * R_REL * 2, qg + 3 * R_REL * 2,
                                      exI, exO);
    k_denom<<<196, 256, 0, stream>>>(offA, exI, exO, rdI, rdO);
    k_agg<<<12500, 256, 0, stream>>>(offA, Pso, exI, exO, NPt2, Pg + 2 * R_REL * 128,
                                     Pg + 3 * R_REL * 128, rdI, rdO, 1, NPt1, be, h1b, out);
}